// Round 3
// baseline (273.460 us; speedup 1.0000x reference)
//
#include <hip/hip_runtime.h>
#include <cstdint>
#include <cstddef>

// PointerNetwork: B=256, S=512, H=128, CHAR/CLASS=10, OUT=64, WE=32
// R4 design (1024-thread k_lstm, 4 waves/SIMD, no AGPR spill of weights):
//  - active-step skipping (char_ids==0, ~51-75/512 steps per row)
//  - thread (q=T&7 k-slice, u=T>>3 unit): owns unit u's 4 gate cols.
//    3-stage DPP bfly8 (xor1/xor2/half-mirror) all-reduce -> gates fused
//    in-lane (x8 redundant, bit-identical across the 8-lane group).
//  - superphase: one barrier per step; L2(a) and L1(a+1) share h1n(a).
//  - per-thread weights 24 x uint4 = 96 VGPRs -> fits 128-reg budget at
//    4 waves/SIMD (launch_bounds(1024,4)); no v_accvgpr traffic.
//  - 3 kernel launches total (prep merged, subject merged into post).

#define SLOTS 192

typedef _Float16 f16x2 __attribute__((ext_vector_type(2)));

__device__ __forceinline__ f16x2 as_h2(unsigned int v) {
    union { unsigned int u; f16x2 h; } x; x.u = v; return x.h;
}

#if __has_builtin(__builtin_amdgcn_fdot2)
__device__ __forceinline__ float fdot2(f16x2 a, f16x2 b, float c) {
    return __builtin_amdgcn_fdot2(a, b, c, false);
}
#else
__device__ __forceinline__ float fdot2(f16x2 a, f16x2 b, float c) {
    return c + (float)a.x * (float)b.x + (float)a.y * (float)b.y;
}
#endif

__device__ __forceinline__ float fast_rcp(float x) {
#if __has_builtin(__builtin_amdgcn_rcpf)
    return __builtin_amdgcn_rcpf(x);
#else
    return 1.f / x;
#endif
}
__device__ __forceinline__ float sigm(float x) {
    x = fminf(fmaxf(x, -30.f), 30.f);
    return fast_rcp(1.f + __expf(-x));
}
__device__ __forceinline__ float tanh_fast(float x) {
    x = fminf(fmaxf(x, -15.f), 15.f);
    float e = __expf(-2.f * x);
    return (1.f - e) * fast_rcp(1.f + e);
}

// xor-butterfly add over lane groups of 8 (q = lane&7) via DPP, VALU-only.
// All 8 lanes end with the group sum (stages commutative-identical).
__device__ __forceinline__ float dpp_bfly8(float v) {
    union { float f; int i; } a, b;
    a.f = v;
    b.i = __builtin_amdgcn_update_dpp(0, a.i, 0xB1, 0xf, 0xf, true);   // quad_perm xor1
    a.f += b.f;
    b.i = __builtin_amdgcn_update_dpp(0, a.i, 0x4E, 0xf, 0xf, true);   // quad_perm xor2
    a.f += b.f;
    b.i = __builtin_amdgcn_update_dpp(0, a.i, 0x141, 0xf, 0xf, true);  // row_half_mirror (xor7≡xor4 here)
    a.f += b.f;
    return a.f;
}

__device__ __forceinline__ float dot_u4(float s, const uint4 h, const uint4 w) {
    s = fdot2(as_h2(h.x), as_h2(w.x), s);
    s = fdot2(as_h2(h.y), as_h2(w.y), s);
    s = fdot2(as_h2(h.z), as_h2(w.z), s);
    s = fdot2(as_h2(h.w), as_h2(w.w), s);
    return s;
}

// ---------------- P0: merged prep: XW1 table + fp16 weight packing -----------
// blocks 0..9: XW1 row for word id = blk (512 threads)
// blocks 10..57: pack W1H/W2H, gid = (blk-10)*512 + T in [0, 24576)
// Layout for 1024-thread k_lstm, thread t = (q=t&7, u=t>>3), col(j)=u+128j:
//  W1H[t*8  + j*2 + m] (m=0..1): elems e: k = 16q + 2*(4m+e) -> l1_Wh rows k,k+1
//  W2H[t*16 + j*4 + m] (m=0..3): kk = 32q + 2*(4m+e);
//      kk<128 -> l2_Wh rows kk (h2 operand), else l2_Wx rows kk-128 (h1n operand)
__global__ __launch_bounds__(512) void k_prep(
    const float* __restrict__ emb_char, const float* __restrict__ emb_word,
    const float* __restrict__ Wwc, const float* __restrict__ bwc,
    const float* __restrict__ l1_Wx, const float* __restrict__ l1_b,
    const float* __restrict__ l1_Wh, const float* __restrict__ l2_Wx,
    const float* __restrict__ l2_Wh,
    float* __restrict__ XW1, uint4* __restrict__ W1H, uint4* __restrict__ W2H)
{
    const int blk = blockIdx.x;
    const int T = threadIdx.x;
    if (blk < 10) {
        __shared__ float xw[64];
        if (T < 64) {
            float acc = emb_char[T] + bwc[T];   // emb_char row 0 (active steps have char==0)
            for (int m = 0; m < 32; ++m) acc += emb_word[blk * 32 + m] * Wwc[m * 64 + T];
            xw[T] = acc;
        }
        __syncthreads();
        float acc = l1_b[T];
        for (int k = 0; k < 64; ++k) acc += xw[k] * l1_Wx[k * 512 + T];
        XW1[blk * 512 + T] = acc;
    } else {
        const int gid = (blk - 10) * 512 + T;  // 0..24575
        union { uint4 qv; f16x2 h[4]; } out;
        if (gid < 8192) {
            const int t = gid >> 3, i = gid & 7;
            const int q = t & 7, u = t >> 3;
            const int j = i >> 1, m = i & 1;
            const int col = u + 128 * j;
            for (int e = 0; e < 4; ++e) {
                const int k = 16 * q + 2 * (4 * m + e);
                f16x2 p;
                p.x = (_Float16)l1_Wh[k * 512 + col];
                p.y = (_Float16)l1_Wh[(k + 1) * 512 + col];
                out.h[e] = p;
            }
            W1H[gid] = out.qv;
        } else {
            const int gid2 = gid - 8192;       // 0..16383
            const int t = gid2 >> 4, i = gid2 & 15;
            const int q = t & 7, u = t >> 3;
            const int j = i >> 2, m = i & 3;
            const int col = u + 128 * j;
            for (int e = 0; e < 4; ++e) {
                const int kk = 32 * q + 2 * (4 * m + e);
                float w0, w1v;
                if (kk < 128) { w0 = l2_Wh[kk * 512 + col];          w1v = l2_Wh[(kk + 1) * 512 + col]; }
                else          { w0 = l2_Wx[(kk - 128) * 512 + col]; w1v = l2_Wx[(kk - 127) * 512 + col]; }
                f16x2 p; p.x = (_Float16)w0; p.y = (_Float16)w1v;
                out.h[e] = p;
            }
            W2H[gid2] = out.qv;
        }
    }
}

// ---------------- main recurrent kernel: 1 block per batch row ---------------
__global__ __launch_bounds__(1024, 4) void k_lstm(
    const int* __restrict__ char_ids, const int* __restrict__ word_ids,
    const float* __restrict__ XW1, const uint4* __restrict__ W1H,
    const uint4* __restrict__ W2H, const float* __restrict__ l2_b,
    float* __restrict__ hbuf, unsigned short* __restrict__ idxbuf)
{
    const int b    = blockIdx.x;
    const int T    = threadIdx.x;   // 0..1023
    const int lane = T & 63;
    const int wv   = T >> 6;        // 0..15
    const int q    = T & 7;         // k-slice 0..7
    const int u    = T >> 3;        // unit 0..127

    __shared__ int   charL[512];
    __shared__ int   wordL[512];
    __shared__ float XW1L[5120];                       // full XW1 table (10x512)
    __shared__ __align__(16) _Float16 h1f[2][128];     // double-buffered h1
    __shared__ __align__(16) _Float16 h2f[2][128];     // double-buffered h2
    __shared__ short actT[512];
    __shared__ short wlist[512];                       // word id per active step
    __shared__ int   ccnt[8];

    if (T < 512) {
        charL[T] = char_ids[b * 512 + T];
        wordL[T] = word_ids[b * 512 + T];
    }
    XW1L[T]        = XW1[T];
    XW1L[1024 + T] = XW1[1024 + T];
    XW1L[2048 + T] = XW1[2048 + T];
    XW1L[3072 + T] = XW1[3072 + T];
    XW1L[4096 + T] = XW1[4096 + T];
    __syncthreads();

    // compact the active-step list (ordered) + write idx map
    const bool act = (T < 512) && (charL[T] == 0);
    const unsigned long long bmask = __ballot(act);
    if (lane == 0 && wv < 8) ccnt[wv] = (int)__popcll(bmask);
    __syncthreads();
    int base = 0;
    {
        const int wcap = wv < 8 ? wv : 8;
        for (int i = 0; i < wcap; ++i) base += ccnt[i];
    }
    int tot = 0;
    for (int i = 0; i < 8; ++i) tot += ccnt[i];
    if (act) {
        const int pos = base + (int)__popcll(bmask & ((1ull << lane) - 1ull));
        actT[pos]  = (short)T;
        wlist[pos] = (short)wordL[T];
    }
    if (T < 512) {
        const int cin = base + (int)__popcll(bmask & ((2ull << lane) - 1ull));
        idxbuf[b * 512 + T] = (unsigned short)(cin < SLOTS - 1 ? cin : SLOTS - 1);
    }
    const int nact = tot;

    // init state
    if (T < 128) {
        h1f[0][T] = (_Float16)0.f;
        h1f[1][T] = (_Float16)0.f;
        h2f[0][T] = (_Float16)0.f;
        h2f[1][T] = (_Float16)0.f;
        hbuf[(size_t)b * SLOTS * 128 + T] = 0.f;   // slot 0 = zeros
    }
    float c1 = 0.f, c2 = 0.f;                      // replicated across the 8-lane group
    const float l2b0 = l2_b[u];
    const float l2b1 = l2_b[128 + u];
    const float l2b2 = l2_b[256 + u];
    const float l2b3 = l2_b[384 + u];

    // persistent fp16 weight slices in VGPRs (24 x uint4 = 96 VGPRs)
    uint4 w1[8], w2[16];
    {
        const uint4* W1t = W1H + (size_t)T * 8;
        const uint4* W2t = W2H + (size_t)T * 16;
#pragma unroll
        for (int i = 0; i < 8; ++i) w1[i] = W1t[i];
#pragma unroll
        for (int i = 0; i < 16; ++i) w2[i] = W2t[i];
    }
#pragma unroll
    for (int i = 0; i < 8; ++i)
        asm volatile("" : "+v"(w1[i].x), "+v"(w1[i].y), "+v"(w1[i].z), "+v"(w1[i].w));
#pragma unroll
    for (int i = 0; i < 16; ++i)
        asm volatile("" : "+v"(w2[i].x), "+v"(w2[i].y), "+v"(w2[i].z), "+v"(w2[i].w));

    __syncthreads();

    // prologue: L1 gates for step 0 (h1 == 0 -> Wh dots are zero, z = xw)
    if (nact > 0) {
        const int w0_ = wlist[0];
        const float zi = XW1L[w0_ * 512 + u];
        const float zg = XW1L[w0_ * 512 + 256 + u];
        const float zo = XW1L[w0_ * 512 + 384 + u];
        c1 = sigm(zi) * tanh_fast(zg);             // c1_old == 0
        const float h1n = sigm(zo) * tanh_fast(c1);
        if (q == 0) h1f[0][u] = (_Float16)h1n;
        __syncthreads();
    }

    // superphase a: reads h1n(a) [H1S], h2(a-1) [H2S];
    //   computes L2(a) -> h2(a) into H2D + hbuf, and L1(a+1) -> h1n(a+1) into H1D.
    // L2 operand slice: concat k in [32q, 32q+32): q<4 -> h2 (Wh), q>=4 -> h1n (Wx).
    // L1 operand slice: h1n halfs [16q, 16q+16).
#define LSTM_STEP(H1S, H2S, H1D, H2D)                                          \
    {                                                                          \
        const uint4* srcL2 = (q < 4) ? ((const uint4*)&H2S[0] + 4 * q)         \
                                     : ((const uint4*)&H1S[0] + 4 * (q - 4));  \
        uint4 sA = srcL2[0], sB = srcL2[1];                                    \
        float p0 = dot_u4(dot_u4(0.f, sA, w2[0]),  sB, w2[1]);                 \
        float p1 = dot_u4(dot_u4(0.f, sA, w2[4]),  sB, w2[5]);                 \
        float p2 = dot_u4(dot_u4(0.f, sA, w2[8]),  sB, w2[9]);                 \
        float p3 = dot_u4(dot_u4(0.f, sA, w2[12]), sB, w2[13]);                \
        sA = srcL2[2]; sB = srcL2[3];                                          \
        p0 = dot_u4(dot_u4(p0, sA, w2[2]),  sB, w2[3]);                        \
        p1 = dot_u4(dot_u4(p1, sA, w2[6]),  sB, w2[7]);                        \
        p2 = dot_u4(dot_u4(p2, sA, w2[10]), sB, w2[11]);                       \
        p3 = dot_u4(dot_u4(p3, sA, w2[14]), sB, w2[15]);                       \
        const float y0 = dpp_bfly8(p0) + l2b0;                                 \
        const float y1 = dpp_bfly8(p1) + l2b1;                                 \
        const float y2 = dpp_bfly8(p2) + l2b2;                                 \
        const float y3 = dpp_bfly8(p3) + l2b3;                                 \
        c2 = sigm(y1) * c2 + sigm(y0) * tanh_fast(y2);                         \
        const float h2v = sigm(y3) * tanh_fast(c2);                            \
        if (q == 0) {                                                          \
            H2D[u] = (_Float16)h2v;                                            \
            const int slot = (a + 1 < SLOTS - 1) ? a + 1 : SLOTS - 1;          \
            hbuf[((size_t)b * SLOTS + slot) * 128 + u] = h2v;                  \
        }                                                                      \
        if (a + 1 < nact) {                                                    \
            const int wid = wlist[a + 1];                                      \
            const uint4* h1s = (const uint4*)&H1S[0] + 2 * q;                  \
            const uint4 tA = h1s[0], tB = h1s[1];                              \
            float r0 = dot_u4(dot_u4(0.f, tA, w1[0]), tB, w1[1]);              \
            float r1 = dot_u4(dot_u4(0.f, tA, w1[2]), tB, w1[3]);              \
            float r2 = dot_u4(dot_u4(0.f, tA, w1[4]), tB, w1[5]);              \
            float r3 = dot_u4(dot_u4(0.f, tA, w1[6]), tB, w1[7]);              \
            const float zi = dpp_bfly8(r0) + XW1L[wid * 512 + u];              \
            const float zf = dpp_bfly8(r1) + XW1L[wid * 512 + 128 + u];        \
            const float zg = dpp_bfly8(r2) + XW1L[wid * 512 + 256 + u];        \
            const float zo = dpp_bfly8(r3) + XW1L[wid * 512 + 384 + u];        \
            c1 = sigm(zf) * c1 + sigm(zi) * tanh_fast(zg);                     \
            const float h1n = sigm(zo) * tanh_fast(c1);                        \
            if (q == 0) H1D[u] = (_Float16)h1n;                                \
        }                                                                      \
        __syncthreads();                                                       \
    }

    int a = 0;
    while (a < nact) {
        LSTM_STEP(h1f[0], h2f[0], h1f[1], h2f[1]);
        ++a;
        if (a >= nact) break;
        LSTM_STEP(h1f[1], h2f[1], h1f[0], h2f[0]);
        ++a;
    }
#undef LSTM_STEP
}

// ---------------- C1: merged subject + LN + po/sub heads + scatter -----------
// beta/gamma computed in-block (replaces k_subject), then
// po(s,o) = rs*sum_c(gm[c]*pw[c][o]*h[s][c]) - u*rs*K2[o] + K1[o]
//   K1[o] = po_b[o] + sum_c bt[c]*pw[c][o];  K2[o] = sum_c gm[c]*pw[c][o]
__global__ __launch_bounds__(256) void k_post(
    const int* __restrict__ subject_ids,
    const unsigned short* __restrict__ idxbuf, const float* __restrict__ hbuf,
    const float* __restrict__ beta_W, const float* __restrict__ beta_b,
    const float* __restrict__ gamma_W, const float* __restrict__ gamma_b,
    const float* __restrict__ sub_W, const float* __restrict__ sub_b,
    const float* __restrict__ po_W, const float* __restrict__ po_b,
    float* __restrict__ out)
{
    const int b = blockIdx.x;
    const int T = threadIdx.x;   // 0..255
    __shared__ float A[20][132];          // A[o][c] = gm[c]*po_W[c*20+o]
    __shared__ float K1[20], K2[20];
    __shared__ float gm[128], bt[128];
    __shared__ float urs[192][2];
    __shared__ float povals[192 * 20];
    __shared__ float subv[192 * 2];
    __shared__ unsigned short idxr[512];
    __shared__ float swl[256];
    __shared__ float subj[256];

    idxr[T] = idxbuf[b * 512 + T];
    idxr[256 + T] = idxbuf[b * 512 + 256 + T];
    swl[T] = sub_W[T];
    {
        const int uu = T & 127, half = T >> 7;
        const int sidx = subject_ids[b * 2 + half];
        const int slot = idxbuf[b * 512 + sidx];
        subj[T] = hbuf[((size_t)b * SLOTS + slot) * 128 + uu];
    }
    __syncthreads();

    // beta (T<128) / gamma (T>=128), identical loop order to old k_subject
    {
        const int uu = T & 127, half = T >> 7;
        const float* __restrict__ W = half ? gamma_W : beta_W;
        float acc = half ? gamma_b[uu] : beta_b[uu];
        for (int c = 0; c < 256; ++c) acc += subj[c] * W[c * 128 + uu];
        if (half) gm[uu] = acc;
        else      bt[uu] = acc;
    }
    __syncthreads();

    // A fill + K1/K2 + per-slot stats & sub head
    for (int i = T; i < 2560; i += 256) {
        const int o = i >> 7, c = i & 127;
        A[o][c] = gm[c] * po_W[c * 20 + o];
    }
    if (T < 20) {
        float k1 = po_b[T], k2 = 0.f;
        for (int c = 0; c < 128; ++c) {
            const float pw = po_W[c * 20 + T];
            k1 += bt[c] * pw;
            k2 += gm[c] * pw;
        }
        K1[T] = k1; K2[T] = k2;
    }
    const int nslot = (int)idxr[511] + 1;
    const float sb0 = sub_b[0], sb1 = sub_b[1];
    for (int s = T; s < nslot; s += 256) {
        const float4* hp4 = (const float4*)(hbuf + ((size_t)b * SLOTS + s) * 128);
        float sum = 0.f, s2 = 0.f, sub0 = sb0, sub1 = sb1;
        for (int c4 = 0; c4 < 32; ++c4) {
            const float4 h = hp4[c4];
            sum += (h.x + h.y) + (h.z + h.w);
            s2  += h.x * h.x + h.y * h.y + h.z * h.z + h.w * h.w;
            const int c = 4 * c4;
            sub0 += h.x * swl[2 * c] + h.y * swl[2 * c + 2] + h.z * swl[2 * c + 4] + h.w * swl[2 * c + 6];
            sub1 += h.x * swl[2 * c + 1] + h.y * swl[2 * c + 3] + h.z * swl[2 * c + 5] + h.w * swl[2 * c + 7];
        }
        const float u = sum * (1.f / 128.f);
        const float v = fmaxf(s2 * (1.f / 128.f) - u * u, 0.f);
        urs[s][0] = u;
        urs[s][1] = 1.f / sqrtf(v + 1e-12f);
        subv[2 * s] = sub0; subv[2 * s + 1] = sub1;
    }
    __syncthreads();

    // po head per (slot, o)
    for (int i = T; i < nslot * 20; i += 256) {
        const int s = i / 20, o = i - 20 * s;
        const float u = urs[s][0], rs = urs[s][1];
        const float4* hp4 = (const float4*)(hbuf + ((size_t)b * SLOTS + s) * 128);
        const float* Ao = &A[o][0];
        float acc = 0.f;
        for (int c4 = 0; c4 < 32; ++c4) {
            const float4 h = hp4[c4];
            const float4 aa = *(const float4*)&Ao[4 * c4];
            acc += h.x * aa.x + h.y * aa.y + h.z * aa.z + h.w * aa.w;
        }
        povals[i] = rs * acc - u * rs * K2[o] + K1[o];
    }
    __syncthreads();

    // scatter
    for (int i = T; i < 2560; i += 256) {
        const int t = i / 5, j = i - 5 * t;
        const int sl = idxr[t];
        const float4 v = *(const float4*)&povals[sl * 20 + 4 * j];
        *(float4*)&out[262144 + ((size_t)(b * 512 + t)) * 20 + 4 * j] = v;
    }
    for (int i = T; i < 512; i += 256) {
        const int sl = idxr[i];
        float2 v; v.x = subv[2 * sl]; v.y = subv[2 * sl + 1];
        *(float2*)&out[((size_t)(b * 512 + i)) * 2] = v;
    }
}

extern "C" void kernel_launch(void* const* d_in, const int* in_sizes, int n_in,
                              void* d_out, int out_size, void* d_ws, size_t ws_size,
                              hipStream_t stream) {
    (void)in_sizes; (void)n_in; (void)out_size; (void)ws_size;
    const int*   char_ids    = (const int*)d_in[0];
    const int*   word_ids    = (const int*)d_in[1];
    const int*   subject_ids = (const int*)d_in[2];
    const float* emb_char    = (const float*)d_in[3];
    const float* emb_word    = (const float*)d_in[4];
    const float* Wwc         = (const float*)d_in[5];
    const float* bwc         = (const float*)d_in[6];
    const float* l1_Wx       = (const float*)d_in[7];
    const float* l1_Wh       = (const float*)d_in[8];
    const float* l1_b        = (const float*)d_in[9];
    const float* l2_Wx       = (const float*)d_in[10];
    const float* l2_Wh       = (const float*)d_in[11];
    const float* l2_b        = (const float*)d_in[12];
    const float* beta_W      = (const float*)d_in[13];
    const float* beta_b      = (const float*)d_in[14];
    const float* gamma_W     = (const float*)d_in[15];
    const float* gamma_b     = (const float*)d_in[16];
    const float* sub_W       = (const float*)d_in[17];
    const float* sub_b       = (const float*)d_in[18];
    const float* po_W        = (const float*)d_in[19];
    const float* po_b        = (const float*)d_in[20];
    float* out = (float*)d_out;

    char* ws = (char*)d_ws;
    float*          XW1    = (float*)(ws + 0);          // 20480 B (pad to 32768)
    uint4*          W1H    = (uint4*)(ws + 32768);      // 131072 B
    uint4*          W2H    = (uint4*)(ws + 163840);     // 262144 B
    unsigned short* idxbuf = (unsigned short*)(ws + 688128);  // 262144 B
    float*          hbuf   = (float*)(ws + 950272);     // 256*192*128*4 = 25165824 B

    k_prep<<<dim3(58), dim3(512), 0, stream>>>(emb_char, emb_word, Wwc, bwc,
                                               l1_Wx, l1_b, l1_Wh, l2_Wx, l2_Wh,
                                               XW1, W1H, W2H);
    k_lstm<<<dim3(256), dim3(1024), 0, stream>>>(char_ids, word_ids, XW1, W1H, W2H,
                                                 l2_b, hbuf, idxbuf);
    k_post<<<dim3(256), dim3(256), 0, stream>>>(subject_ids, idxbuf, hbuf,
                                                beta_W, beta_b, gamma_W, gamma_b,
                                                sub_W, sub_b, po_W, po_b, out);
}

// Round 4
// 232.642 us; speedup vs baseline: 1.1755x; 1.1755x over previous
//
#include <hip/hip_runtime.h>
#include <cstdint>
#include <cstddef>

// PointerNetwork: B=256, S=512, H=128, CHAR/CLASS=10, OUT=64, WE=32
// R5 design (R3's proven 512-thread superphase k_lstm + fused epilogue):
//  - k_lstm identical to R3 (121.8 us measured): 4-way k-slice, fused gates,
//    1 barrier/step superphase, 192 fp16 weight VGPRs.
//  - h-history kept in LDS (128 slots x 132-pad f32); hbuf/idxbuf global
//    buffers DELETED; k_post logic fused as block epilogue -> 2 launches,
//    ws shrinks 26.1 MB -> 0.43 MB.

#define HIST 128
#define HPAD 132

typedef _Float16 f16x2 __attribute__((ext_vector_type(2)));

__device__ __forceinline__ f16x2 as_h2(unsigned int v) {
    union { unsigned int u; f16x2 h; } x; x.u = v; return x.h;
}

#if __has_builtin(__builtin_amdgcn_fdot2)
__device__ __forceinline__ float fdot2(f16x2 a, f16x2 b, float c) {
    return __builtin_amdgcn_fdot2(a, b, c, false);
}
#else
__device__ __forceinline__ float fdot2(f16x2 a, f16x2 b, float c) {
    return c + (float)a.x * (float)b.x + (float)a.y * (float)b.y;
}
#endif

__device__ __forceinline__ float fast_rcp(float x) {
#if __has_builtin(__builtin_amdgcn_rcpf)
    return __builtin_amdgcn_rcpf(x);
#else
    return 1.f / x;
#endif
}
__device__ __forceinline__ float sigm(float x) {
    x = fminf(fmaxf(x, -30.f), 30.f);
    return fast_rcp(1.f + __expf(-x));
}
__device__ __forceinline__ float tanh_fast(float x) {
    x = fminf(fmaxf(x, -15.f), 15.f);
    float e = __expf(-2.f * x);
    return (1.f - e) * fast_rcp(1.f + e);
}

// xor-butterfly add over quads (q = lane&3) via DPP quad_perm, VALU-only.
__device__ __forceinline__ float dpp_bfly4(float v) {
    union { float f; int i; } a, b;
    a.f = v;
    b.i = __builtin_amdgcn_update_dpp(0, a.i, 0xB1, 0xf, 0xf, true);   // quad_perm xor1
    a.f += b.f;
    b.i = __builtin_amdgcn_update_dpp(0, a.i, 0x4E, 0xf, 0xf, true);   // quad_perm xor2
    a.f += b.f;
    return a.f;
}

__device__ __forceinline__ float dot_u4(float s, const uint4 h, const uint4 w) {
    s = fdot2(as_h2(h.x), as_h2(w.x), s);
    s = fdot2(as_h2(h.y), as_h2(w.y), s);
    s = fdot2(as_h2(h.z), as_h2(w.z), s);
    s = fdot2(as_h2(h.w), as_h2(w.w), s);
    return s;
}

// ---------------- P0: merged prep: XW1 table + fp16 weight packing -----------
// blocks 0..9: XW1 row for word id = blk.  blocks 10..57: pack W1H/W2H.
// thread t = (q=t&3, u=t>>2); col(j) = u + 128*j (j = gate i/f/g/o)
// W1H[t*16 + j*4 + m]: elems e: k = 32q + 2*(4m+e) -> l1_Wh rows k,k+1
// W2H[t*32 + ph*16 + j*4 + m]: ph=0 -> l2_Wh rows (h2-half)
//                              ph=1 -> l2_Wx rows (h1n-half)
__global__ __launch_bounds__(512) void k_prep(
    const float* __restrict__ emb_char, const float* __restrict__ emb_word,
    const float* __restrict__ Wwc, const float* __restrict__ bwc,
    const float* __restrict__ l1_Wx, const float* __restrict__ l1_b,
    const float* __restrict__ l1_Wh, const float* __restrict__ l2_Wx,
    const float* __restrict__ l2_Wh,
    float* __restrict__ XW1, uint4* __restrict__ W1H, uint4* __restrict__ W2H)
{
    const int blk = blockIdx.x;
    const int T = threadIdx.x;
    if (blk < 10) {
        __shared__ float xw[64];
        if (T < 64) {
            float acc = emb_char[T] + bwc[T];   // emb_char row 0 (active steps have char==0)
            for (int m = 0; m < 32; ++m) acc += emb_word[blk * 32 + m] * Wwc[m * 64 + T];
            xw[T] = acc;
        }
        __syncthreads();
        float acc = l1_b[T];
        for (int k = 0; k < 64; ++k) acc += xw[k] * l1_Wx[k * 512 + T];
        XW1[blk * 512 + T] = acc;
    } else {
        const int gid = (blk - 10) * 512 + T;  // 0..24575
        union { uint4 qv; f16x2 h[4]; } out;
        if (gid < 8192) {
            const int t = gid >> 4, i = gid & 15;
            const int q = t & 3, u = t >> 2;
            const int j = i >> 2, m = i & 3;
            const int col = u + 128 * j;
            for (int e = 0; e < 4; ++e) {
                const int k = 32 * q + 2 * (4 * m + e);
                f16x2 p;
                p.x = (_Float16)l1_Wh[k * 512 + col];
                p.y = (_Float16)l1_Wh[(k + 1) * 512 + col];
                out.h[e] = p;
            }
            W1H[gid] = out.qv;
        } else {
            const int gid2 = gid - 8192;       // 0..16383
            const int t = gid2 >> 5, i = gid2 & 31;
            const int q = t & 3, u = t >> 2;
            const int ph = i >> 4, jm = i & 15;
            const int j = jm >> 2, m = jm & 3;
            const int col = u + 128 * j;
            const float* __restrict__ src = ph ? l2_Wx : l2_Wh;
            for (int e = 0; e < 4; ++e) {
                const int k = 32 * q + 2 * (4 * m + e);
                f16x2 p;
                p.x = (_Float16)src[k * 512 + col];
                p.y = (_Float16)src[(k + 1) * 512 + col];
                out.h[e] = p;
            }
            W2H[gid2] = out.qv;
        }
    }
}

// ---------------- main kernel: recurrence + fused epilogue, 1 block/row ------
__global__ __launch_bounds__(512, 2) void k_lstm(
    const int* __restrict__ char_ids, const int* __restrict__ word_ids,
    const int* __restrict__ subject_ids,
    const float* __restrict__ XW1, const uint4* __restrict__ W1H,
    const uint4* __restrict__ W2H, const float* __restrict__ l2_b,
    const float* __restrict__ beta_W, const float* __restrict__ beta_b,
    const float* __restrict__ gamma_W, const float* __restrict__ gamma_b,
    const float* __restrict__ sub_W, const float* __restrict__ sub_b,
    const float* __restrict__ po_W, const float* __restrict__ po_b,
    float* __restrict__ out)
{
    const int b    = blockIdx.x;
    const int T    = threadIdx.x;   // 0..511
    const int lane = T & 63;
    const int wv   = T >> 6;        // 0..7
    const int q    = T & 3;         // k-slice 0..3
    const int u    = T >> 2;        // unit 0..127

    // recurrence state
    __shared__ int   charL[512];
    __shared__ int   wordL[512];
    __shared__ float XW1L[5120];                       // full XW1 table (10x512)
    __shared__ __align__(16) _Float16 h1f[2][128];     // double-buffered h1
    __shared__ __align__(16) _Float16 h2f[2][128];     // double-buffered h2
    __shared__ short actT[512];
    __shared__ short wlist[512];
    __shared__ unsigned short idxL[512];               // timestep -> slot map
    __shared__ int   ccnt[8];
    // h-history in LDS (replaces global hbuf); padded stride vs bank conflicts
    __shared__ __align__(16) float hl[HIST * HPAD];    // 67584 B
    // epilogue workspace
    __shared__ float A[20][132];
    __shared__ float K1[20], K2[20];
    __shared__ float gm[128], bt[128];
    __shared__ float urs[HIST][2];
    __shared__ float povals[HIST * 20];
    __shared__ float subv[HIST * 2];
    __shared__ float swl[256];
    __shared__ float subj[256];

    charL[T] = char_ids[b * 512 + T];
    wordL[T] = word_ids[b * 512 + T];
#pragma unroll
    for (int i = 0; i < 10; ++i) XW1L[i * 512 + T] = XW1[i * 512 + T];
    __syncthreads();

    // compact the active-step list (ordered) + slot map
    const bool act = (charL[T] == 0);
    const unsigned long long bmask = __ballot(act);
    if (lane == 0) ccnt[wv] = (int)__popcll(bmask);
    __syncthreads();
    int base = 0;
    for (int i = 0; i < wv; ++i) base += ccnt[i];
    int tot = base;
    for (int i = wv; i < 8; ++i) tot += ccnt[i];
    if (act) {
        const int pos = base + (int)__popcll(bmask & ((1ull << lane) - 1ull));
        actT[pos]  = (short)T;
        wlist[pos] = (short)wordL[T];
    }
    {
        const int cin = base + (int)__popcll(bmask & ((2ull << lane) - 1ull));
        idxL[T] = (unsigned short)(cin < HIST - 1 ? cin : HIST - 1);
    }
    const int nact = tot;

    // init state
    if (T < 128) {
        h1f[0][T] = (_Float16)0.f;
        h1f[1][T] = (_Float16)0.f;
        h2f[0][T] = (_Float16)0.f;
        h2f[1][T] = (_Float16)0.f;
        hl[T]     = 0.f;                  // slot 0 = zeros
    }
    float c1 = 0.f, c2 = 0.f;             // replicated across the quad
    const float l2b0 = l2_b[u];
    const float l2b1 = l2_b[128 + u];
    const float l2b2 = l2_b[256 + u];
    const float l2b3 = l2_b[384 + u];

    // persistent fp16 weight slices in VGPRs (48 x uint4 = 192 VGPRs)
    uint4 w1[16], w2[32];
    {
        const uint4* W1t = W1H + (size_t)T * 16;
        const uint4* W2t = W2H + (size_t)T * 32;
#pragma unroll
        for (int i = 0; i < 16; ++i) w1[i] = W1t[i];
#pragma unroll
        for (int i = 0; i < 32; ++i) w2[i] = W2t[i];
    }
#pragma unroll
    for (int i = 0; i < 16; ++i)
        asm volatile("" : "+v"(w1[i].x), "+v"(w1[i].y), "+v"(w1[i].z), "+v"(w1[i].w));
#pragma unroll
    for (int i = 0; i < 32; ++i)
        asm volatile("" : "+v"(w2[i].x), "+v"(w2[i].y), "+v"(w2[i].z), "+v"(w2[i].w));

    __syncthreads();

    // prologue: L1 gates for step 0 (h1 == 0 -> Wh dots are zero, z = xw)
    if (nact > 0) {
        const int w0_ = wlist[0];
        const float zi = XW1L[w0_ * 512 + u];
        const float zg = XW1L[w0_ * 512 + 256 + u];
        const float zo = XW1L[w0_ * 512 + 384 + u];
        c1 = sigm(zi) * tanh_fast(zg);             // c1_old == 0
        const float h1n = sigm(zo) * tanh_fast(c1);
        if (q == 0) h1f[0][u] = (_Float16)h1n;
        __syncthreads();
    }

    // superphase a: reads h1n(a) [H1S], h2(a-1) [H2S];
    //   computes L2(a) -> h2(a) into H2D + hl, and L1(a+1) -> h1n(a+1) into H1D.
#define LSTM_STEP(H1S, H2S, H1D, H2D)                                          \
    {                                                                          \
        const uint4* h1r = (const uint4*)&H1S[0] + 4 * q;                      \
        const uint4 a0 = h1r[0], a1 = h1r[1], a2 = h1r[2], a3 = h1r[3];        \
        const uint4* h2r = (const uint4*)&H2S[0] + 4 * q;                      \
        const uint4 g0 = h2r[0], g1 = h2r[1], g2 = h2r[2], g3 = h2r[3];        \
        const bool more = (a + 1 < nact);                                      \
        const int wid = more ? wlist[a + 1] : 0;                               \
        const float xwi = XW1L[wid * 512 + u];                                 \
        const float xwf = XW1L[wid * 512 + 128 + u];                           \
        const float xwg = XW1L[wid * 512 + 256 + u];                           \
        const float xwo = XW1L[wid * 512 + 384 + u];                           \
        float p[4];                                                            \
        _Pragma("unroll")                                                      \
        for (int j = 0; j < 4; ++j) {                                          \
            float s = dot_u4(0.f, g0, w2[4 * j + 0]);                          \
            s = dot_u4(s, g1, w2[4 * j + 1]);                                  \
            s = dot_u4(s, g2, w2[4 * j + 2]);                                  \
            s = dot_u4(s, g3, w2[4 * j + 3]);                                  \
            s = dot_u4(s, a0, w2[16 + 4 * j + 0]);                             \
            s = dot_u4(s, a1, w2[16 + 4 * j + 1]);                             \
            s = dot_u4(s, a2, w2[16 + 4 * j + 2]);                             \
            s = dot_u4(s, a3, w2[16 + 4 * j + 3]);                             \
            p[j] = s;                                                          \
        }                                                                      \
        const float y0 = dpp_bfly4(p[0]) + l2b0;                               \
        const float y1 = dpp_bfly4(p[1]) + l2b1;                               \
        const float y2 = dpp_bfly4(p[2]) + l2b2;                               \
        const float y3 = dpp_bfly4(p[3]) + l2b3;                               \
        c2 = sigm(y1) * c2 + sigm(y0) * tanh_fast(y2);                         \
        const float h2v = sigm(y3) * tanh_fast(c2);                            \
        if (q == 0) {                                                          \
            H2D[u] = (_Float16)h2v;                                            \
            const int slot = (a + 1 < HIST - 1) ? a + 1 : HIST - 1;            \
            hl[slot * HPAD + u] = h2v;                                         \
        }                                                                      \
        if (more) {                                                            \
            float r0, r1, r2, r3;                                              \
            {                                                                  \
                float r = dot_u4(0.f, a0, w1[0]);                              \
                r = dot_u4(r, a1, w1[1]);                                      \
                r = dot_u4(r, a2, w1[2]);                                      \
                r = dot_u4(r, a3, w1[3]);                                      \
                r0 = r;                                                        \
                r = dot_u4(0.f, a0, w1[4]);                                    \
                r = dot_u4(r, a1, w1[5]);                                      \
                r = dot_u4(r, a2, w1[6]);                                      \
                r = dot_u4(r, a3, w1[7]);                                      \
                r1 = r;                                                        \
                r = dot_u4(0.f, a0, w1[8]);                                    \
                r = dot_u4(r, a1, w1[9]);                                      \
                r = dot_u4(r, a2, w1[10]);                                     \
                r = dot_u4(r, a3, w1[11]);                                     \
                r2 = r;                                                        \
                r = dot_u4(0.f, a0, w1[12]);                                   \
                r = dot_u4(r, a1, w1[13]);                                     \
                r = dot_u4(r, a2, w1[14]);                                     \
                r = dot_u4(r, a3, w1[15]);                                     \
                r3 = r;                                                        \
            }                                                                  \
            const float zi = dpp_bfly4(r0) + xwi;                              \
            const float zf = dpp_bfly4(r1) + xwf;                              \
            const float zg = dpp_bfly4(r2) + xwg;                              \
            const float zo = dpp_bfly4(r3) + xwo;                              \
            c1 = sigm(zf) * c1 + sigm(zi) * tanh_fast(zg);                     \
            const float h1n = sigm(zo) * tanh_fast(c1);                        \
            if (q == 0) H1D[u] = (_Float16)h1n;                                \
        }                                                                      \
        __syncthreads();                                                       \
    }

    int a = 0;
    while (a < nact) {
        LSTM_STEP(h1f[0], h2f[0], h1f[1], h2f[1]);
        ++a;
        if (a >= nact) break;
        LSTM_STEP(h1f[1], h2f[1], h1f[0], h2f[0]);
        ++a;
    }
#undef LSTM_STEP

    // ================= fused epilogue (was k_subject + k_out2) ===============
    // hl holds the full h-history; idxL the timestep->slot map.
    if (T < 256) {
        swl[T] = sub_W[T];
        const int uu = T & 127, half = T >> 7;
        const int sidx = subject_ids[b * 2 + half];
        const int slot = idxL[sidx];
        subj[T] = hl[slot * HPAD + uu];
    }
    __syncthreads();

    // beta (T<128) / gamma (128<=T<256), same loop order as before
    if (T < 256) {
        const int uu = T & 127, half = T >> 7;
        const float* __restrict__ W = half ? gamma_W : beta_W;
        float acc = half ? gamma_b[uu] : beta_b[uu];
        for (int c = 0; c < 256; ++c) acc += subj[c] * W[c * 128 + uu];
        if (half) gm[uu] = acc;
        else      bt[uu] = acc;
    }
    __syncthreads();

    // A fill + K1/K2 + per-slot stats & sub head
    for (int i = T; i < 2560; i += 512) {
        const int o = i >> 7, c = i & 127;
        A[o][c] = gm[c] * po_W[c * 20 + o];
    }
    if (T < 20) {
        float k1 = po_b[T], k2 = 0.f;
        for (int c = 0; c < 128; ++c) {
            const float pw = po_W[c * 20 + T];
            k1 += bt[c] * pw;
            k2 += gm[c] * pw;
        }
        K1[T] = k1; K2[T] = k2;
    }
    const int nslot = (int)idxL[511] + 1;
    const float sb0 = sub_b[0], sb1 = sub_b[1];
    for (int s = T; s < nslot; s += 512) {
        const float4* hp4 = (const float4*)&hl[s * HPAD];
        float sum = 0.f, s2 = 0.f, sub0 = sb0, sub1 = sb1;
        for (int c4 = 0; c4 < 32; ++c4) {
            const float4 h = hp4[c4];
            sum += (h.x + h.y) + (h.z + h.w);
            s2  += h.x * h.x + h.y * h.y + h.z * h.z + h.w * h.w;
            const int c = 4 * c4;
            sub0 += h.x * swl[2 * c] + h.y * swl[2 * c + 2] + h.z * swl[2 * c + 4] + h.w * swl[2 * c + 6];
            sub1 += h.x * swl[2 * c + 1] + h.y * swl[2 * c + 3] + h.z * swl[2 * c + 5] + h.w * swl[2 * c + 7];
        }
        const float mu = sum * (1.f / 128.f);
        const float vv = fmaxf(s2 * (1.f / 128.f) - mu * mu, 0.f);
        urs[s][0] = mu;
        urs[s][1] = 1.f / sqrtf(vv + 1e-12f);
        subv[2 * s] = sub0; subv[2 * s + 1] = sub1;
    }
    __syncthreads();

    // po head per (slot, o)
    for (int i = T; i < nslot * 20; i += 512) {
        const int s = i / 20, o = i - 20 * s;
        const float mu = urs[s][0], rs = urs[s][1];
        const float4* hp4 = (const float4*)&hl[s * HPAD];
        const float* Ao = &A[o][0];
        float acc = 0.f;
        for (int c4 = 0; c4 < 32; ++c4) {
            const float4 h = hp4[c4];
            const float4 aa = *(const float4*)&Ao[4 * c4];
            acc += h.x * aa.x + h.y * aa.y + h.z * aa.z + h.w * aa.w;
        }
        povals[i] = rs * acc - mu * rs * K2[o] + K1[o];
    }
    __syncthreads();

    // scatter
    for (int i = T; i < 2560; i += 512) {
        const int t = i / 5, j = i - 5 * t;
        const int sl = idxL[t];
        const float4 v = *(const float4*)&povals[sl * 20 + 4 * j];
        *(float4*)&out[262144 + ((size_t)(b * 512 + t)) * 20 + 4 * j] = v;
    }
    for (int i = T; i < 512; i += 512) {
        const int sl = idxL[i];
        float2 v; v.x = subv[2 * sl]; v.y = subv[2 * sl + 1];
        *(float2*)&out[((size_t)(b * 512 + i)) * 2] = v;
    }
}

extern "C" void kernel_launch(void* const* d_in, const int* in_sizes, int n_in,
                              void* d_out, int out_size, void* d_ws, size_t ws_size,
                              hipStream_t stream) {
    (void)in_sizes; (void)n_in; (void)out_size; (void)ws_size;
    const int*   char_ids    = (const int*)d_in[0];
    const int*   word_ids    = (const int*)d_in[1];
    const int*   subject_ids = (const int*)d_in[2];
    const float* emb_char    = (const float*)d_in[3];
    const float* emb_word    = (const float*)d_in[4];
    const float* Wwc         = (const float*)d_in[5];
    const float* bwc         = (const float*)d_in[6];
    const float* l1_Wx       = (const float*)d_in[7];
    const float* l1_Wh       = (const float*)d_in[8];
    const float* l1_b        = (const float*)d_in[9];
    const float* l2_Wx       = (const float*)d_in[10];
    const float* l2_Wh       = (const float*)d_in[11];
    const float* l2_b        = (const float*)d_in[12];
    const float* beta_W      = (const float*)d_in[13];
    const float* beta_b      = (const float*)d_in[14];
    const float* gamma_W     = (const float*)d_in[15];
    const float* gamma_b     = (const float*)d_in[16];
    const float* sub_W       = (const float*)d_in[17];
    const float* sub_b       = (const float*)d_in[18];
    const float* po_W        = (const float*)d_in[19];
    const float* po_b        = (const float*)d_in[20];
    float* out = (float*)d_out;

    char* ws = (char*)d_ws;
    float* XW1 = (float*)(ws + 0);          // 20480 B (pad to 32768)
    uint4* W1H = (uint4*)(ws + 32768);      // 131072 B
    uint4* W2H = (uint4*)(ws + 163840);     // 262144 B -> ws total 425984 B

    k_prep<<<dim3(58), dim3(512), 0, stream>>>(emb_char, emb_word, Wwc, bwc,
                                               l1_Wx, l1_b, l1_Wh, l2_Wx, l2_Wh,
                                               XW1, W1H, W2H);
    k_lstm<<<dim3(256), dim3(512), 0, stream>>>(char_ids, word_ids, subject_ids,
                                                XW1, W1H, W2H, l2_b,
                                                beta_W, beta_b, gamma_W, gamma_b,
                                                sub_W, sub_b, po_W, po_b, out);
}

// Round 5
// 203.253 us; speedup vs baseline: 1.3454x; 1.1446x over previous
//
#include <hip/hip_runtime.h>
#include <cstdint>
#include <cstddef>

// PointerNetwork: B=256, S=512, H=128, CHAR/CLASS=10, OUT=64, WE=32
// R6 design (MFMA M=1 recurrence + R5 fused epilogue):
//  - per wave (8 waves): 4 N-tiles = its 16 units x 4 gates. z for unit
//    16w+(lane&15) lands on reg0 of lanes 0-15 (C layout col=lane&15,
//    row=(lane>>4)*4+reg; row 0 only is real at M=1). All 4 gate z's for a
//    unit on ONE lane -> gates in-lane, no reduce, no DPP.
//  - weights as MFMA B-frags in AGPR-eligible regs (192/thread), packed by
//    k_prep with the same k-slab formula as the A-side LDS reads.
//  - superphase (1 barrier/step): L2(a) and L1(a+1) share h1n(a); hcat LDS
//    double buffer [h2 | h1n].
//  - h-history + epilogue (subject/LN/heads/scatter) in-kernel as R5.

#define HIST 128
#define HPAD 132

typedef _Float16 f16x8 __attribute__((ext_vector_type(8)));
typedef float    f32x4 __attribute__((ext_vector_type(4)));

__device__ __forceinline__ f16x8 as_h8(const uint4& v) {
    f16x8 r; __builtin_memcpy(&r, &v, 16); return r;
}

#define MFMA16(a, b, c) __builtin_amdgcn_mfma_f32_16x16x32_f16((a), (b), (c), 0, 0, 0)

__device__ __forceinline__ float fast_rcp(float x) {
#if __has_builtin(__builtin_amdgcn_rcpf)
    return __builtin_amdgcn_rcpf(x);
#else
    return 1.f / x;
#endif
}
__device__ __forceinline__ float sigm(float x) {
    x = fminf(fmaxf(x, -30.f), 30.f);
    return fast_rcp(1.f + __expf(-x));
}
__device__ __forceinline__ float tanh_fast(float x) {
    x = fminf(fmaxf(x, -15.f), 15.f);
    float e = __expf(-2.f * x);
    return (1.f - e) * fast_rcp(1.f + e);
}

// ---------------- P0: merged prep: XW1 table + MFMA B-frag packing -----------
// blocks 0..9: XW1 row for word id = blk.  blocks 10..57: pack WF.
// k_lstm thread thr = (w=thr>>6, l=thr&63); frag f: 0..31 L2 (j=f>>3, ks=f&7),
// 32..47 L1 (j=(f-32)>>2, ks=(f-32)&3). col = j*128 + 16w + (l&15);
// elems e: k = ks*32 + 8*(l>>4) + e.
// L2 k<128 -> l2_Wh row k (h2 half), else l2_Wx row k-128 (h1n half).
__global__ __launch_bounds__(512) void k_prep(
    const float* __restrict__ emb_char, const float* __restrict__ emb_word,
    const float* __restrict__ Wwc, const float* __restrict__ bwc,
    const float* __restrict__ l1_Wx, const float* __restrict__ l1_b,
    const float* __restrict__ l1_Wh, const float* __restrict__ l2_Wx,
    const float* __restrict__ l2_Wh,
    float* __restrict__ XW1, uint4* __restrict__ WF)
{
    const int blk = blockIdx.x;
    const int T = threadIdx.x;
    if (blk < 10) {
        __shared__ float xw[64];
        if (T < 64) {
            float acc = emb_char[T] + bwc[T];   // emb_char row 0 (active steps have char==0)
            for (int m = 0; m < 32; ++m) acc += emb_word[blk * 32 + m] * Wwc[m * 64 + T];
            xw[T] = acc;
        }
        __syncthreads();
        float acc = l1_b[T];
        for (int k = 0; k < 64; ++k) acc += xw[k] * l1_Wx[k * 512 + T];
        XW1[blk * 512 + T] = acc;
    } else {
        const int gid = (blk - 10) * 512 + T;   // 0..24575 frags
        const int thr = gid / 48;
        const int f   = gid - thr * 48;
        const int w   = thr >> 6, l = thr & 63;
        const int kb  = 8 * (l >> 4);
        const bool isL2 = (f < 32);
        int j, ks;
        if (isL2) { j = f >> 3; ks = f & 7; }
        else      { const int f2 = f - 32; j = f2 >> 2; ks = f2 & 3; }
        const int col = j * 128 + 16 * w + (l & 15);
        union { uint4 qv; _Float16 h[8]; } o;
        for (int e = 0; e < 8; ++e) {
            const int k = ks * 32 + kb + e;
            float v;
            if (isL2) v = (k < 128) ? l2_Wh[k * 512 + col] : l2_Wx[(k - 128) * 512 + col];
            else      v = l1_Wh[k * 512 + col];
            o.h[e] = (_Float16)v;
        }
        WF[gid] = o.qv;   // gid == thr*48 + f
    }
}

// ---------------- main kernel: MFMA recurrence + fused epilogue --------------
__global__ __launch_bounds__(512, 2) void k_lstm(
    const int* __restrict__ char_ids, const int* __restrict__ word_ids,
    const int* __restrict__ subject_ids,
    const float* __restrict__ XW1, const uint4* __restrict__ WF,
    const float* __restrict__ l2_b,
    const float* __restrict__ beta_W, const float* __restrict__ beta_b,
    const float* __restrict__ gamma_W, const float* __restrict__ gamma_b,
    const float* __restrict__ sub_W, const float* __restrict__ sub_b,
    const float* __restrict__ po_W, const float* __restrict__ po_b,
    float* __restrict__ out)
{
    const int b    = blockIdx.x;
    const int T    = threadIdx.x;   // 0..511
    const int lane = T & 63;
    const int wv   = T >> 6;        // wave 0..7
    const int kb   = 8 * (lane >> 4);          // k-slab base within 32
    const int unit = 16 * wv + (lane & 15);    // this lane's unit (lanes<16 real)
    const bool g16 = (lane < 16);

    __shared__ int   charL[512];
    __shared__ int   wordL[512];
    __shared__ float XW1L[5120];                        // 10x512 XW1 table
    __shared__ __align__(16) _Float16 hcat[2][256];     // [h2 | h1n] dbuf
    __shared__ short wlist[512];
    __shared__ unsigned short idxL[512];
    __shared__ int   ccnt[8];
    __shared__ __align__(16) float hl[HIST * HPAD];     // h-history (f32)
    // epilogue workspace
    __shared__ float A[20][132];
    __shared__ float K1[20], K2[20];
    __shared__ float gm[128], bt[128];
    __shared__ float urs[HIST][2];
    __shared__ float povals[HIST * 20];
    __shared__ float subv[HIST * 2];
    __shared__ float swl[256];
    __shared__ float subj[256];

    charL[T] = char_ids[b * 512 + T];
    wordL[T] = word_ids[b * 512 + T];
#pragma unroll
    for (int i = 0; i < 10; ++i) XW1L[i * 512 + T] = XW1[i * 512 + T];
    __syncthreads();

    // compact active-step list (ordered) + slot map
    const bool act = (charL[T] == 0);
    const unsigned long long bmask = __ballot(act);
    if (lane == 0) ccnt[wv] = (int)__popcll(bmask);
    __syncthreads();
    int base = 0;
    for (int i = 0; i < wv; ++i) base += ccnt[i];
    int tot = base;
    for (int i = wv; i < 8; ++i) tot += ccnt[i];
    if (act) {
        const int pos = base + (int)__popcll(bmask & ((1ull << lane) - 1ull));
        wlist[pos] = (short)wordL[T];
    }
    {
        const int cin = base + (int)__popcll(bmask & ((2ull << lane) - 1ull));
        idxL[T] = (unsigned short)(cin < HIST - 1 ? cin : HIST - 1);
    }
    const int nact = tot;

    // init state
    if (T < 128) {
        hcat[0][T] = (_Float16)0.f;   // h2(-1) = 0
        hl[T]      = 0.f;             // slot 0 = zeros
    }
    float c1 = 0.f, c2 = 0.f;         // valid on lanes<16
    const float l2b0 = l2_b[unit];
    const float l2b1 = l2_b[128 + unit];
    const float l2b2 = l2_b[256 + unit];
    const float l2b3 = l2_b[384 + unit];

    // persistent MFMA B-fragments (48 x uint4 = 192 regs, AGPR-eligible)
    uint4 wf[48];
    {
        const uint4* p = WF + (size_t)T * 48;
#pragma unroll
        for (int i = 0; i < 48; ++i) wf[i] = p[i];
    }
    __syncthreads();

    // prologue: L1 gates for step 0 (h1 == 0 -> z = xw)
    if (nact > 0) {
        const int w0_ = wlist[0];
        const float zi = XW1L[w0_ * 512 + unit];
        const float zg = XW1L[w0_ * 512 + 256 + unit];
        const float zo = XW1L[w0_ * 512 + 384 + unit];
        c1 = sigm(zi) * tanh_fast(zg);            // c1_old == 0
        const float h1n = sigm(zo) * tanh_fast(c1);
        if (g16) hcat[0][128 + unit] = (_Float16)h1n;
        __syncthreads();
    }

    // superphase a: hcat[cur] = [h2(a-1) | h1n(a)].
    //   L2(a): z = bias + hcat[cur]*W2  -> h2(a) -> hcat[nxt][unit] + hl
    //   L1(a+1): z = xw(a+1) + h1n(a)*W1h -> h1n(a+1) -> hcat[nxt][128+unit]
    int cur = 0;
    for (int a = 0; a < nact; ++a) {
        const _Float16* hc = hcat[cur];
        _Float16*       hn = hcat[cur ^ 1];

        // ---- L2: 4 gate-tiles, K=256 chained MFMA ----
        f32x4 acc0 = {l2b0, 0.f, 0.f, 0.f};
        f32x4 acc1 = {l2b1, 0.f, 0.f, 0.f};
        f32x4 acc2 = {l2b2, 0.f, 0.f, 0.f};
        f32x4 acc3 = {l2b3, 0.f, 0.f, 0.f};
#pragma unroll
        for (int ks = 0; ks < 8; ++ks) {
            const f16x8 aa = *(const f16x8*)&hc[kb + 32 * ks];
            acc0 = MFMA16(aa, as_h8(wf[0 * 8 + ks]), acc0);
            acc1 = MFMA16(aa, as_h8(wf[1 * 8 + ks]), acc1);
            acc2 = MFMA16(aa, as_h8(wf[2 * 8 + ks]), acc2);
            acc3 = MFMA16(aa, as_h8(wf[3 * 8 + ks]), acc3);
        }
        if (g16) {
            c2 = sigm(acc1[0]) * c2 + sigm(acc0[0]) * tanh_fast(acc2[0]);
            const float h2v = sigm(acc3[0]) * tanh_fast(c2);
            hn[unit] = (_Float16)h2v;
            const int slot = (a + 1 < HIST - 1) ? a + 1 : HIST - 1;
            hl[slot * HPAD + unit] = h2v;
        }

        // ---- L1 for step a+1: K=128 over h1n(a) ----
        if (a + 1 < nact) {
            const int wid = wlist[a + 1];
            f32x4 r0 = {XW1L[wid * 512 + unit],       0.f, 0.f, 0.f};
            f32x4 r1 = {XW1L[wid * 512 + 128 + unit], 0.f, 0.f, 0.f};
            f32x4 r2 = {XW1L[wid * 512 + 256 + unit], 0.f, 0.f, 0.f};
            f32x4 r3 = {XW1L[wid * 512 + 384 + unit], 0.f, 0.f, 0.f};
#pragma unroll
            for (int ks = 0; ks < 4; ++ks) {
                const f16x8 aa = *(const f16x8*)&hc[128 + kb + 32 * ks];
                r0 = MFMA16(aa, as_h8(wf[32 + 0 * 4 + ks]), r0);
                r1 = MFMA16(aa, as_h8(wf[32 + 1 * 4 + ks]), r1);
                r2 = MFMA16(aa, as_h8(wf[32 + 2 * 4 + ks]), r2);
                r3 = MFMA16(aa, as_h8(wf[32 + 3 * 4 + ks]), r3);
            }
            if (g16) {
                c1 = sigm(r1[0]) * c1 + sigm(r0[0]) * tanh_fast(r2[0]);
                const float h1n = sigm(r3[0]) * tanh_fast(c1);
                hn[128 + unit] = (_Float16)h1n;
            }
        }
        __syncthreads();
        cur ^= 1;
    }

    // ================= fused epilogue (identical to R5) ======================
    if (T < 256) {
        swl[T] = sub_W[T];
        const int uu = T & 127, half = T >> 7;
        const int sidx = subject_ids[b * 2 + half];
        const int slot = idxL[sidx];
        subj[T] = hl[slot * HPAD + uu];
    }
    __syncthreads();

    if (T < 256) {
        const int uu = T & 127, half = T >> 7;
        const float* __restrict__ W = half ? gamma_W : beta_W;
        float acc = half ? gamma_b[uu] : beta_b[uu];
        for (int c = 0; c < 256; ++c) acc += subj[c] * W[c * 128 + uu];
        if (half) gm[uu] = acc;
        else      bt[uu] = acc;
    }
    __syncthreads();

    for (int i = T; i < 2560; i += 512) {
        const int o = i >> 7, c = i & 127;
        A[o][c] = gm[c] * po_W[c * 20 + o];
    }
    if (T < 20) {
        float k1 = po_b[T], k2 = 0.f;
        for (int c = 0; c < 128; ++c) {
            const float pw = po_W[c * 20 + T];
            k1 += bt[c] * pw;
            k2 += gm[c] * pw;
        }
        K1[T] = k1; K2[T] = k2;
    }
    const int nslot = (int)idxL[511] + 1;
    const float sb0 = sub_b[0], sb1 = sub_b[1];
    for (int s = T; s < nslot; s += 512) {
        const float4* hp4 = (const float4*)&hl[s * HPAD];
        float sum = 0.f, s2 = 0.f, sub0 = sb0, sub1 = sb1;
        for (int c4 = 0; c4 < 32; ++c4) {
            const float4 h = hp4[c4];
            sum += (h.x + h.y) + (h.z + h.w);
            s2  += h.x * h.x + h.y * h.y + h.z * h.z + h.w * h.w;
            const int c = 4 * c4;
            sub0 += h.x * swl[2 * c] + h.y * swl[2 * c + 2] + h.z * swl[2 * c + 4] + h.w * swl[2 * c + 6];
            sub1 += h.x * swl[2 * c + 1] + h.y * swl[2 * c + 3] + h.z * swl[2 * c + 5] + h.w * swl[2 * c + 7];
        }
        const float mu = sum * (1.f / 128.f);
        const float vv = fmaxf(s2 * (1.f / 128.f) - mu * mu, 0.f);
        urs[s][0] = mu;
        urs[s][1] = 1.f / sqrtf(vv + 1e-12f);
        subv[2 * s] = sub0; subv[2 * s + 1] = sub1;
    }
    __syncthreads();

    for (int i = T; i < nslot * 20; i += 512) {
        const int s = i / 20, o = i - 20 * s;
        const float mu = urs[s][0], rs = urs[s][1];
        const float4* hp4 = (const float4*)&hl[s * HPAD];
        const float* Ao = &A[o][0];
        float acc = 0.f;
        for (int c4 = 0; c4 < 32; ++c4) {
            const float4 h = hp4[c4];
            const float4 aa = *(const float4*)&Ao[4 * c4];
            acc += h.x * aa.x + h.y * aa.y + h.z * aa.z + h.w * aa.w;
        }
        povals[i] = rs * acc - mu * rs * K2[o] + K1[o];
    }
    __syncthreads();

    for (int i = T; i < 2560; i += 512) {
        const int t = i / 5, j = i - 5 * t;
        const int sl = idxL[t];
        const float4 v = *(const float4*)&povals[sl * 20 + 4 * j];
        *(float4*)&out[262144 + ((size_t)(b * 512 + t)) * 20 + 4 * j] = v;
    }
    for (int i = T; i < 512; i += 512) {
        const int sl = idxL[i];
        float2 v; v.x = subv[2 * sl]; v.y = subv[2 * sl + 1];
        *(float2*)&out[((size_t)(b * 512 + i)) * 2] = v;
    }
}

extern "C" void kernel_launch(void* const* d_in, const int* in_sizes, int n_in,
                              void* d_out, int out_size, void* d_ws, size_t ws_size,
                              hipStream_t stream) {
    (void)in_sizes; (void)n_in; (void)out_size; (void)ws_size;
    const int*   char_ids    = (const int*)d_in[0];
    const int*   word_ids    = (const int*)d_in[1];
    const int*   subject_ids = (const int*)d_in[2];
    const float* emb_char    = (const float*)d_in[3];
    const float* emb_word    = (const float*)d_in[4];
    const float* Wwc         = (const float*)d_in[5];
    const float* bwc         = (const float*)d_in[6];
    const float* l1_Wx       = (const float*)d_in[7];
    const float* l1_b        = (const float*)d_in[9];
    const float* l1_Wh       = (const float*)d_in[8];
    const float* l2_Wx       = (const float*)d_in[10];
    const float* l2_Wh       = (const float*)d_in[11];
    const float* l2_b        = (const float*)d_in[12];
    const float* beta_W      = (const float*)d_in[13];
    const float* beta_b      = (const float*)d_in[14];
    const float* gamma_W     = (const float*)d_in[15];
    const float* gamma_b     = (const float*)d_in[16];
    const float* sub_W       = (const float*)d_in[17];
    const float* sub_b       = (const float*)d_in[18];
    const float* po_W        = (const float*)d_in[19];
    const float* po_b        = (const float*)d_in[20];
    float* out = (float*)d_out;

    char* ws = (char*)d_ws;
    float* XW1 = (float*)(ws + 0);          // 20480 B (pad to 32768)
    uint4* WF  = (uint4*)(ws + 32768);      // 24576*16 = 393216 B -> ws 425984 B

    k_prep<<<dim3(58), dim3(512), 0, stream>>>(emb_char, emb_word, Wwc, bwc,
                                               l1_Wx, l1_b, l1_Wh, l2_Wx, l2_Wh,
                                               XW1, WF);
    k_lstm<<<dim3(256), dim3(512), 0, stream>>>(char_ids, word_ids, subject_ids,
                                                XW1, WF, l2_b,
                                                beta_W, beta_b, gamma_W, gamma_b,
                                                sub_W, sub_b, po_W, po_b, out);
}